// Round 2
// baseline (692.076 us; speedup 1.0000x reference)
//
#include <hip/hip_runtime.h>

// TransformerBlock on MI355X (gfx950). Inputs/outputs fp32 (per reference);
// internal compute bf16 MFMA with fp32 accumulation.
// B=2 S=2048 D=1024 H=16 Dh=64 HIDDEN=4096, causal attention, exact GELU.
//
// Round 2: fp32 I/O fix. Pipeline:
//   cast weights fp32->bf16 (ws) -> LN1 -> QKV GEMMs -> flash attention
//   -> Wo GEMM (+x residual, fp32 out) -> LN2 -> W1 GEMM (+GELU)
//   -> W2 GEMM (+x1 residual, fp32 out to d_out)
// Workspace (80 MB):
//   [ 0, 2M) wq_b   [ 2, 4M) wk_b   [ 4, 6M) wv_b  [ 6, 8M) wo_b
//   [ 8,16M) w1_b   [16,24M) w2_b
//   [24,32M) h      [32,40M) q      [40,48M) k     [48,56M) v
//   [56,64M) ctx / h2
//   [64,80M) x1 (fp32)
//   g (bf16, 32MB) reuses [24,56M)

typedef __bf16 bf16x8_t __attribute__((ext_vector_type(8)));
typedef float f32x4_t __attribute__((ext_vector_type(4)));
typedef unsigned short u16x8 __attribute__((ext_vector_type(8)));

__device__ __forceinline__ unsigned short f2b(float f) {
    unsigned int u = __builtin_bit_cast(unsigned int, f);
    u += 0x7fffu + ((u >> 16) & 1u);   // round-to-nearest-even
    return (unsigned short)(u >> 16);
}
__device__ __forceinline__ float b2f(unsigned short u) {
    unsigned int v = ((unsigned int)u) << 16;
    return __builtin_bit_cast(float, v);
}
__device__ __forceinline__ bf16x8_t as_bf(u16x8 v) {
    return __builtin_bit_cast(bf16x8_t, v);
}
__device__ __forceinline__ void store_out(float* p, float v) { *p = v; }
__device__ __forceinline__ void store_out(unsigned short* p, float v) { *p = f2b(v); }

// ---------------------------------------------------------------- cast
__global__ __launch_bounds__(256) void cast_kernel(
    const float* __restrict__ src, unsigned short* __restrict__ dst, int n) {
    const int i = (blockIdx.x * 256 + threadIdx.x) * 8;
    if (i >= n) return;
    float4 a = *(const float4*)(src + i);
    float4 b = *(const float4*)(src + i + 4);
    u16x8 o;
    o[0] = f2b(a.x); o[1] = f2b(a.y); o[2] = f2b(a.z); o[3] = f2b(a.w);
    o[4] = f2b(b.x); o[5] = f2b(b.y); o[6] = f2b(b.z); o[7] = f2b(b.w);
    *(u16x8*)(dst + i) = o;
}

// ---------------------------------------------------------------- LayerNorm
__global__ __launch_bounds__(256) void ln_kernel(
    const float* __restrict__ X,
    const float* __restrict__ scale,
    const float* __restrict__ shift,
    unsigned short* __restrict__ Hout) {
    const int tok = blockIdx.x;
    const int tid = threadIdx.x;
    const size_t base = (size_t)tok * 1024 + tid * 4;
    float4 xv = *(const float4*)(X + base);
    float f[4] = {xv.x, xv.y, xv.z, xv.w};
    float s = 0.f, s2 = 0.f;
#pragma unroll
    for (int i = 0; i < 4; i++) { s += f[i]; s2 += f[i] * f[i]; }
#pragma unroll
    for (int off = 32; off >= 1; off >>= 1) {
        s += __shfl_down(s, off);
        s2 += __shfl_down(s2, off);
    }
    __shared__ float red[8];
    const int wv = tid >> 6;
    if ((tid & 63) == 0) { red[wv] = s; red[4 + wv] = s2; }
    __syncthreads();
    s = red[0] + red[1] + red[2] + red[3];
    s2 = red[4] + red[5] + red[6] + red[7];
    const float mean = s * (1.f / 1024.f);
    const float var = s2 * (1.f / 1024.f) - mean * mean;
    const float rstd = rsqrtf(var + 1e-5f);
    const float4 sc = *(const float4*)(scale + tid * 4);
    const float4 sh = *(const float4*)(shift + tid * 4);
    u16x8 dummy;
    unsigned short ov[4];
    ov[0] = f2b((f[0] - mean) * rstd * sc.x + sh.x);
    ov[1] = f2b((f[1] - mean) * rstd * sc.y + sh.y);
    ov[2] = f2b((f[2] - mean) * rstd * sc.z + sh.z);
    ov[3] = f2b((f[3] - mean) * rstd * sc.w + sh.w);
    (void)dummy;
    *(unsigned long long*)(Hout + base) = *(unsigned long long*)ov;
}

// ---------------------------------------------------------------- GEMM
// C[M,N] = A[M,K](bf16) @ B[K,N](bf16) + bias(f32) (+res(f32) / gelu).
#define BM 128
#define BN 128
#define BK 32
#define LDT_G 40  // padded LDS K-stride (elements); 40*2=80B keeps 16B align

template <int EPI, typename OutT>
__global__ __launch_bounds__(256) void gemm_kernel(
    const unsigned short* __restrict__ A, const unsigned short* __restrict__ Bw,
    const float* __restrict__ bias, const float* __restrict__ res,
    OutT* __restrict__ C, int M, int N, int K) {
    __shared__ __align__(16) unsigned short As[BM * LDT_G];
    __shared__ __align__(16) unsigned short Bs[BN * LDT_G];
    const int tid = threadIdx.x;
    const int wave = tid >> 6, lane = tid & 63;
    const int quad = lane >> 4, l16 = lane & 15;
    const int bm = blockIdx.x * BM, bn = blockIdx.y * BN;
    const int wm = (wave & 1) * 64, wn = (wave >> 1) * 64;

    f32x4_t acc[4][4];
#pragma unroll
    for (int i = 0; i < 4; i++)
#pragma unroll
        for (int j = 0; j < 4; j++) acc[i][j] = f32x4_t{0.f, 0.f, 0.f, 0.f};

    const int arow = tid >> 1, acol = (tid & 1) * 16;
    const int bkk = tid >> 3, bn0 = (tid & 7) * 16;

    for (int k0 = 0; k0 < K; k0 += BK) {
        // stage A tile [BM][BK]
        {
            const unsigned short* src = A + (size_t)(bm + arow) * K + k0 + acol;
            u16x8 v0 = *(const u16x8*)src;
            u16x8 v1 = *(const u16x8*)(src + 8);
            *(u16x8*)&As[arow * LDT_G + acol] = v0;
            *(u16x8*)&As[arow * LDT_G + acol + 8] = v1;
        }
        // stage B tile transposed: Bs[n][kk] = B[k0+kk][bn+n]
        {
            const unsigned short* src = Bw + (size_t)(k0 + bkk) * N + bn + bn0;
            u16x8 v0 = *(const u16x8*)src;
            u16x8 v1 = *(const u16x8*)(src + 8);
#pragma unroll
            for (int i = 0; i < 8; i++) Bs[(bn0 + i) * LDT_G + bkk] = v0[i];
#pragma unroll
            for (int i = 0; i < 8; i++) Bs[(bn0 + 8 + i) * LDT_G + bkk] = v1[i];
        }
        __syncthreads();
        bf16x8_t af[4], bfr[4];
#pragma unroll
        for (int i = 0; i < 4; i++) {
            af[i] = as_bf(*(const u16x8*)&As[(wm + i * 16 + l16) * LDT_G + quad * 8]);
            bfr[i] = as_bf(*(const u16x8*)&Bs[(wn + i * 16 + l16) * LDT_G + quad * 8]);
        }
#pragma unroll
        for (int i = 0; i < 4; i++)
#pragma unroll
            for (int j = 0; j < 4; j++)
                acc[i][j] = __builtin_amdgcn_mfma_f32_16x16x32_bf16(af[i], bfr[j], acc[i][j], 0, 0, 0);
        __syncthreads();
    }

    // epilogue: C/D layout col=l16, row=quad*4+r
#pragma unroll
    for (int i = 0; i < 4; i++) {
        const int row = bm + wm + i * 16 + quad * 4;
#pragma unroll
        for (int j = 0; j < 4; j++) {
            const int col = bn + wn + j * 16 + l16;
            const float bv = bias[col];
#pragma unroll
            for (int r = 0; r < 4; r++) {
                float v = acc[i][j][r] + bv;
                if (EPI == 1) v += res[(size_t)(row + r) * N + col];
                if (EPI == 2) v = 0.5f * v * (1.f + erff(v * 0.70710678118f));
                store_out(&C[(size_t)(row + r) * N + col], v);
            }
        }
    }
}

// ---------------------------------------------------------------- Attention
// q,k,v,ctx: [B*S, 1024] bf16 with head h at columns h*64..h*64+63.
#define LDT_A 72

__global__ __launch_bounds__(256) void attn_kernel(
    const unsigned short* __restrict__ Q, const unsigned short* __restrict__ K,
    const unsigned short* __restrict__ V, unsigned short* __restrict__ O) {
    __shared__ __align__(16) unsigned short Ks[64 * LDT_A];
    __shared__ __align__(16) unsigned short Vs[64 * LDT_A];  // Vs[d][key]
    __shared__ __align__(16) unsigned short Ps[64 * LDT_A];  // per-wave 16-row slabs
    const int tid = threadIdx.x;
    const int w = tid >> 6, lane = tid & 63;
    const int quad = lane >> 4, l16 = lane & 15;
    const int qblk = blockIdx.x, hh = blockIdx.y, bb = blockIdx.z;
    const int q0 = qblk * 64;
    const size_t seqbase = (size_t)bb * 2048;
    const int hoff = hh * 64;

    // Q fragments (A-layout: m=l16, k=quad*8+j), d split 0..31 / 32..63
    const unsigned short* qrow = Q + (seqbase + q0 + w * 16 + l16) * 1024 + hoff;
    const bf16x8_t qf0 = as_bf(*(const u16x8*)(qrow + quad * 8));
    const bf16x8_t qf1 = as_bf(*(const u16x8*)(qrow + 32 + quad * 8));

    f32x4_t o[4];
#pragma unroll
    for (int jd = 0; jd < 4; jd++) o[jd] = f32x4_t{0.f, 0.f, 0.f, 0.f};
    float m_r[4], l_r[4];
#pragma unroll
    for (int r = 0; r < 4; r++) { m_r[r] = -1e30f; l_r[r] = 0.f; }

    const int srow = tid >> 2;         // 0..63
    const int scol = (tid & 3) * 16;   // 0,16,32,48
    const int rowg = q0 + w * 16 + quad * 4;

    for (int t = 0; t <= qblk; ++t) {
        // ---- stage K (row-major) and V (transposed) tiles
        {
            const unsigned short* ksrc = K + (seqbase + t * 64 + srow) * 1024 + hoff + scol;
            const unsigned short* vsrc = V + (seqbase + t * 64 + srow) * 1024 + hoff + scol;
            u16x8 k0v = *(const u16x8*)ksrc;
            u16x8 k1v = *(const u16x8*)(ksrc + 8);
            u16x8 v0v = *(const u16x8*)vsrc;
            u16x8 v1v = *(const u16x8*)(vsrc + 8);
            *(u16x8*)&Ks[srow * LDT_A + scol] = k0v;
            *(u16x8*)&Ks[srow * LDT_A + scol + 8] = k1v;
#pragma unroll
            for (int i = 0; i < 8; i++) Vs[(scol + i) * LDT_A + srow] = v0v[i];
#pragma unroll
            for (int i = 0; i < 8; i++) Vs[(scol + 8 + i) * LDT_A + srow] = v1v[i];
        }
        __syncthreads();

        // ---- S = Q @ K^T  (B-frag of K^T == A-layout read of K rows)
        f32x4_t s[4];
#pragma unroll
        for (int jn = 0; jn < 4; jn++) {
            bf16x8_t kf0 = as_bf(*(const u16x8*)&Ks[(jn * 16 + l16) * LDT_A + quad * 8]);
            bf16x8_t kf1 = as_bf(*(const u16x8*)&Ks[(jn * 16 + l16) * LDT_A + 32 + quad * 8]);
            f32x4_t z = f32x4_t{0.f, 0.f, 0.f, 0.f};
            z = __builtin_amdgcn_mfma_f32_16x16x32_bf16(qf0, kf0, z, 0, 0, 0);
            z = __builtin_amdgcn_mfma_f32_16x16x32_bf16(qf1, kf1, z, 0, 0, 0);
            s[jn] = z;
        }
        // ---- scale + causal mask
#pragma unroll
        for (int jn = 0; jn < 4; jn++) {
            const int col = t * 64 + jn * 16 + l16;
#pragma unroll
            for (int r = 0; r < 4; r++) {
                float val = s[jn][r] * 0.125f;
                s[jn][r] = (col <= rowg + r) ? val : -1e30f;
            }
        }
        // ---- online softmax (rows live in quad groups; reduce over l16)
        float alpha[4];
#pragma unroll
        for (int r = 0; r < 4; r++) {
            float mx = fmaxf(fmaxf(s[0][r], s[1][r]), fmaxf(s[2][r], s[3][r]));
            mx = fmaxf(mx, __shfl_xor(mx, 1));
            mx = fmaxf(mx, __shfl_xor(mx, 2));
            mx = fmaxf(mx, __shfl_xor(mx, 4));
            mx = fmaxf(mx, __shfl_xor(mx, 8));
            const float mnew = fmaxf(m_r[r], mx);
            alpha[r] = __expf(m_r[r] - mnew);
            m_r[r] = mnew;
            float sum = 0.f;
#pragma unroll
            for (int jn = 0; jn < 4; jn++) {
                float p = __expf(s[jn][r] - mnew);
                s[jn][r] = p;
                sum += p;
            }
            sum += __shfl_xor(sum, 1);
            sum += __shfl_xor(sum, 2);
            sum += __shfl_xor(sum, 4);
            sum += __shfl_xor(sum, 8);
            l_r[r] = l_r[r] * alpha[r] + sum;
#pragma unroll
            for (int jd = 0; jd < 4; jd++) o[jd][r] *= alpha[r];
        }
        // ---- P: C-layout regs -> LDS (bf16) -> A-layout frags (wave-private slab)
#pragma unroll
        for (int jn = 0; jn < 4; jn++)
#pragma unroll
            for (int r = 0; r < 4; r++)
                Ps[(w * 16 + quad * 4 + r) * LDT_A + jn * 16 + l16] = f2b(s[jn][r]);
        const bf16x8_t pf0 = as_bf(*(const u16x8*)&Ps[(w * 16 + l16) * LDT_A + quad * 8]);
        const bf16x8_t pf1 = as_bf(*(const u16x8*)&Ps[(w * 16 + l16) * LDT_A + 32 + quad * 8]);
        // ---- O += P @ V   (B-frag of V from transposed Vs[d][key])
#pragma unroll
        for (int jd = 0; jd < 4; jd++) {
            bf16x8_t vf0 = as_bf(*(const u16x8*)&Vs[(jd * 16 + l16) * LDT_A + quad * 8]);
            bf16x8_t vf1 = as_bf(*(const u16x8*)&Vs[(jd * 16 + l16) * LDT_A + 32 + quad * 8]);
            o[jd] = __builtin_amdgcn_mfma_f32_16x16x32_bf16(pf0, vf0, o[jd], 0, 0, 0);
            o[jd] = __builtin_amdgcn_mfma_f32_16x16x32_bf16(pf1, vf1, o[jd], 0, 0, 0);
        }
        __syncthreads();
    }

    // ---- epilogue: ctx[b,s,h*64+d]
#pragma unroll
    for (int jd = 0; jd < 4; jd++)
#pragma unroll
        for (int r = 0; r < 4; r++) {
            float val = o[jd][r] / l_r[r];
            O[(seqbase + rowg + r) * 1024 + hoff + jd * 16 + l16] = f2b(val);
        }
}

// ---------------------------------------------------------------- launch
extern "C" void kernel_launch(void* const* d_in, const int* in_sizes, int n_in,
                              void* d_out, int out_size, void* d_ws, size_t ws_size,
                              hipStream_t stream) {
    const float* x = (const float*)d_in[0];
    const float* ln1s = (const float*)d_in[1];
    const float* ln1b = (const float*)d_in[2];
    const float* ln2s = (const float*)d_in[3];
    const float* ln2b = (const float*)d_in[4];
    const float* wq = (const float*)d_in[5];
    const float* bq = (const float*)d_in[6];
    const float* wk = (const float*)d_in[7];
    const float* bk = (const float*)d_in[8];
    const float* wv = (const float*)d_in[9];
    const float* bv = (const float*)d_in[10];
    const float* wo = (const float*)d_in[11];
    const float* bo = (const float*)d_in[12];
    const float* w1 = (const float*)d_in[13];
    const float* b1 = (const float*)d_in[14];
    const float* w2 = (const float*)d_in[15];
    const float* b2 = (const float*)d_in[16];
    float* out = (float*)d_out;

    char* ws = (char*)d_ws;
    const size_t MB = 1u << 20;
    unsigned short* wqb = (unsigned short*)(ws + 0 * MB);
    unsigned short* wkb = (unsigned short*)(ws + 2 * MB);
    unsigned short* wvb = (unsigned short*)(ws + 4 * MB);
    unsigned short* wob = (unsigned short*)(ws + 6 * MB);
    unsigned short* w1b = (unsigned short*)(ws + 8 * MB);
    unsigned short* w2b = (unsigned short*)(ws + 16 * MB);
    unsigned short* h   = (unsigned short*)(ws + 24 * MB);
    unsigned short* qb  = (unsigned short*)(ws + 32 * MB);
    unsigned short* kb  = (unsigned short*)(ws + 40 * MB);
    unsigned short* vb  = (unsigned short*)(ws + 48 * MB);
    unsigned short* ctx = (unsigned short*)(ws + 56 * MB);
    unsigned short* h2  = (unsigned short*)(ws + 56 * MB);  // reuses ctx
    float*          x1  = (float*)(ws + 64 * MB);           // fp32, 16MB
    unsigned short* g   = (unsigned short*)(ws + 24 * MB);  // reuses h,q,k,v (32MB)

    const dim3 blk(256);
    const int NW = 1024 * 1024;   // 1M elements per attention weight

    // 0) weights fp32 -> bf16
    cast_kernel<<<NW / 2048, blk, 0, stream>>>(wq, wqb, NW);
    cast_kernel<<<NW / 2048, blk, 0, stream>>>(wk, wkb, NW);
    cast_kernel<<<NW / 2048, blk, 0, stream>>>(wv, wvb, NW);
    cast_kernel<<<NW / 2048, blk, 0, stream>>>(wo, wob, NW);
    cast_kernel<<<4 * NW / 2048, blk, 0, stream>>>(w1, w1b, 4 * NW);
    cast_kernel<<<4 * NW / 2048, blk, 0, stream>>>(w2, w2b, 4 * NW);

    // 1) h = LN1(x)
    ln_kernel<<<4096, blk, 0, stream>>>(x, ln1s, ln1b, h);
    // 2) q,k,v = h @ W + b      (M=4096,N=1024,K=1024)
    gemm_kernel<0, unsigned short><<<dim3(32, 8), blk, 0, stream>>>(h, wqb, bq, nullptr, qb, 4096, 1024, 1024);
    gemm_kernel<0, unsigned short><<<dim3(32, 8), blk, 0, stream>>>(h, wkb, bk, nullptr, kb, 4096, 1024, 1024);
    gemm_kernel<0, unsigned short><<<dim3(32, 8), blk, 0, stream>>>(h, wvb, bv, nullptr, vb, 4096, 1024, 1024);
    // 3) ctx = causal_attention(q,k,v)
    attn_kernel<<<dim3(32, 16, 2), blk, 0, stream>>>(qb, kb, vb, ctx);
    // 4) x1 = ctx @ wo + bo + x   (fp32 out)
    gemm_kernel<1, float><<<dim3(32, 8), blk, 0, stream>>>(ctx, wob, bo, x, x1, 4096, 1024, 1024);
    // 5) h2 = LN2(x1)
    ln_kernel<<<4096, blk, 0, stream>>>(x1, ln2s, ln2b, h2);
    // 6) g = gelu(h2 @ w1 + b1)  (M=4096,N=4096,K=1024)
    gemm_kernel<2, unsigned short><<<dim3(32, 32), blk, 0, stream>>>(h2, w1b, b1, nullptr, g, 4096, 4096, 1024);
    // 7) out = g @ w2 + b2 + x1  (M=4096,N=1024,K=4096, fp32 out)
    gemm_kernel<1, float><<<dim3(32, 8), blk, 0, stream>>>(g, w2b, b2, x1, out, 4096, 1024, 4096);
}

// Round 3
// 553.655 us; speedup vs baseline: 1.2500x; 1.2500x over previous
//
#include <hip/hip_runtime.h>

// TransformerBlock on MI355X (gfx950). fp32 I/O, bf16 MFMA compute.
// B=2 S=2048 D=1024 H=16 Dh=64 HIDDEN=4096, causal, exact GELU.
//
// Round 3: async-pipelined GEMM.
//   - Weights pre-transposed+cast once per call ([N][K] bf16) -> GEMM stages
//     both operands with global_load_lds(16B) into fragment-ordered LDS
//     subtiles (16 rows x 32 cols = 1KB = one wave issue; ds_read_b128 at
//     lane*16 -> conflict-free), double-buffered, ONE barrier per K-step:
//       issue glds(k+1)->buf^1; ds_read+MFMA on buf; __syncthreads; swap.
//     The barrier's vmcnt(0) drain IS the prefetch completion wait -> global
//     latency overlaps MFMA instead of serializing after it.
//   - QKV fused into one M=4096 N=3072 GEMM (768 blocks, 3/CU).
//   - N=1024 GEMMs (Wo, W2) use BN=64 tiles -> 512 blocks, 2/CU.
// Workspace (80 MB):
//   [ 0, 6M) wqkv^T   [ 6, 8M) wo^T   [ 8,16M) w1^T   [16,24M) w2^T
//   [24,32M) h -> h2  [32,56M) qkv -> g(32MB spans [32,64M))
//   [56,64M) ctx      [64,80M) x1 (fp32)

typedef __bf16 bf16x8_t __attribute__((ext_vector_type(8)));
typedef float f32x4_t __attribute__((ext_vector_type(4)));
typedef unsigned short u16x8 __attribute__((ext_vector_type(8)));

__device__ __forceinline__ unsigned short f2b(float f) {
    unsigned int u = __builtin_bit_cast(unsigned int, f);
    u += 0x7fffu + ((u >> 16) & 1u);   // round-to-nearest-even
    return (unsigned short)(u >> 16);
}
__device__ __forceinline__ bf16x8_t as_bf(u16x8 v) {
    return __builtin_bit_cast(bf16x8_t, v);
}
__device__ __forceinline__ void store_out(float* p, float v) { *p = v; }
__device__ __forceinline__ void store_out(unsigned short* p, float v) { *p = f2b(v); }

// async global->LDS, 16B per lane; lds dest must be wave-uniform base
__device__ __forceinline__ void glds16(const unsigned short* g, unsigned short* l) {
    __builtin_amdgcn_global_load_lds(
        (const __attribute__((address_space(1))) unsigned int*)g,
        (__attribute__((address_space(3))) unsigned int*)l, 16, 0, 0);
}

// -------------------------------------------------- transpose + cast weights
// src [K][N] fp32 -> dst [N][K] bf16
__global__ __launch_bounds__(256) void transpose_cast(
    const float* __restrict__ src, unsigned short* __restrict__ dst,
    int K, int N) {
    __shared__ float tile[32][33];
    const int k0 = blockIdx.x * 32, n0 = blockIdx.y * 32;
    const int c = threadIdx.x & 31, r8 = threadIdx.x >> 5;
#pragma unroll
    for (int i = 0; i < 4; i++) {
        const int r = r8 + i * 8;
        tile[r][c] = src[(size_t)(k0 + r) * N + n0 + c];
    }
    __syncthreads();
#pragma unroll
    for (int i = 0; i < 4; i++) {
        const int rr = r8 + i * 8;
        dst[(size_t)(n0 + rr) * K + k0 + c] = f2b(tile[c][rr]);
    }
}

// ---------------------------------------------------------------- LayerNorm
__global__ __launch_bounds__(256) void ln_kernel(
    const float* __restrict__ X,
    const float* __restrict__ scale,
    const float* __restrict__ shift,
    unsigned short* __restrict__ Hout) {
    const int tok = blockIdx.x;
    const int tid = threadIdx.x;
    const size_t base = (size_t)tok * 1024 + tid * 4;
    float4 xv = *(const float4*)(X + base);
    float f[4] = {xv.x, xv.y, xv.z, xv.w};
    float s = 0.f, s2 = 0.f;
#pragma unroll
    for (int i = 0; i < 4; i++) { s += f[i]; s2 += f[i] * f[i]; }
#pragma unroll
    for (int off = 32; off >= 1; off >>= 1) {
        s += __shfl_down(s, off);
        s2 += __shfl_down(s2, off);
    }
    __shared__ float red[8];
    const int wv = tid >> 6;
    if ((tid & 63) == 0) { red[wv] = s; red[4 + wv] = s2; }
    __syncthreads();
    s = red[0] + red[1] + red[2] + red[3];
    s2 = red[4] + red[5] + red[6] + red[7];
    const float mean = s * (1.f / 1024.f);
    const float var = s2 * (1.f / 1024.f) - mean * mean;
    const float rstd = rsqrtf(var + 1e-5f);
    const float4 sc = *(const float4*)(scale + tid * 4);
    const float4 sh = *(const float4*)(shift + tid * 4);
    unsigned short ov[4];
    ov[0] = f2b((f[0] - mean) * rstd * sc.x + sh.x);
    ov[1] = f2b((f[1] - mean) * rstd * sc.y + sh.y);
    ov[2] = f2b((f[2] - mean) * rstd * sc.z + sh.z);
    ov[3] = f2b((f[3] - mean) * rstd * sc.w + sh.w);
    *(unsigned long long*)(Hout + base) = *(unsigned long long*)ov;
}

// ---------------------------------------------------------------- GEMM
// C[M,N] = A[M,K](bf16) @ Bt[N,K]^T(bf16) + bias (+res / gelu).
// BM=128 fixed; BN template (128 or 64). 4 waves, wave tile 64 x BN/2.
// LDS subtile s (16 rows x 32 cols): lane q*16+l holds row s*16+l, cols q*8..+7.
template <int BN, int EPI, typename OutT>
__global__ __launch_bounds__(256) void gemm_kernel(
    const unsigned short* __restrict__ A, const unsigned short* __restrict__ Bt,
    const float* __restrict__ bp0, const float* __restrict__ bp1,
    const float* __restrict__ bp2, const float* __restrict__ bp3,
    const float* __restrict__ res, OutT* __restrict__ C, int M, int N, int K) {
    constexpr int BSUB = BN / 16;
    constexpr int JF = BN / 32;
    __shared__ __align__(16) unsigned short As[2][8 * 512];
    __shared__ __align__(16) unsigned short Bs[2][BSUB * 512];
    const int tid = threadIdx.x;
    const int w = tid >> 6, lane = tid & 63;
    const int quad = lane >> 4, l16 = lane & 15;
    const int bm = blockIdx.x * 128, bn = blockIdx.y * BN;
    const int wm = (w & 1) * 64, wn = (w >> 1) * (BN / 2);

    f32x4_t acc[4][JF];
#pragma unroll
    for (int i = 0; i < 4; i++)
#pragma unroll
        for (int j = 0; j < JF; j++) acc[i][j] = f32x4_t{0.f, 0.f, 0.f, 0.f};

    // per-lane global source for subtile 0 at k=0
    const unsigned short* Abase = A + (size_t)(bm + l16) * K + quad * 8;
    const unsigned short* Bbase = Bt + (size_t)(bn + l16) * K + quad * 8;

    // prologue: fill buf 0
    {
        for (int s = w; s < 8; s += 4)
            glds16(Abase + (size_t)s * 16 * K, &As[0][s * 512]);
        for (int s = w; s < BSUB; s += 4)
            glds16(Bbase + (size_t)s * 16 * K, &Bs[0][s * 512]);
    }
    __syncthreads();

    int buf = 0;
    for (int k0 = 0; k0 < K; k0 += 32) {
        if (k0 + 32 < K) {
            const int kn = k0 + 32;
            for (int s = w; s < 8; s += 4)
                glds16(Abase + (size_t)s * 16 * K + kn, &As[buf ^ 1][s * 512]);
            for (int s = w; s < BSUB; s += 4)
                glds16(Bbase + (size_t)s * 16 * K + kn, &Bs[buf ^ 1][s * 512]);
        }
        bf16x8_t af[4], bfv[JF];
#pragma unroll
        for (int i = 0; i < 4; i++)
            af[i] = as_bf(*(const u16x8*)&As[buf][((wm >> 4) + i) * 512 + lane * 8]);
#pragma unroll
        for (int j = 0; j < JF; j++)
            bfv[j] = as_bf(*(const u16x8*)&Bs[buf][((wn >> 4) + j) * 512 + lane * 8]);
#pragma unroll
        for (int i = 0; i < 4; i++)
#pragma unroll
            for (int j = 0; j < JF; j++)
                acc[i][j] = __builtin_amdgcn_mfma_f32_16x16x32_bf16(af[i], bfv[j], acc[i][j], 0, 0, 0);
        __syncthreads();   // drains vmcnt -> buf^1 ready; waves done reading buf
        buf ^= 1;
    }

    // epilogue: C/D layout col=l16, row=quad*4+r
#pragma unroll
    for (int i = 0; i < 4; i++) {
        const int row = bm + wm + i * 16 + quad * 4;
#pragma unroll
        for (int j = 0; j < JF; j++) {
            const int col = bn + wn + j * 16 + l16;
            const int sel = col >> 10;
            const float* bp = (sel == 0) ? bp0 : (sel == 1) ? bp1 : (sel == 2) ? bp2 : bp3;
            const float bv = bp[col & 1023];
#pragma unroll
            for (int r = 0; r < 4; r++) {
                float v = acc[i][j][r] + bv;
                if (EPI == 1) v += res[(size_t)(row + r) * N + col];
                if (EPI == 2) v = 0.5f * v * (1.f + erff(v * 0.70710678118f));
                store_out(&C[(size_t)(row + r) * N + col], v);
            }
        }
    }
}

// ---------------------------------------------------------------- Attention
// q,k,v: rows of stride ld (fused qkv buffer); ctx out stride 1024.
#define LDT_A 72

__global__ __launch_bounds__(256) void attn_kernel(
    const unsigned short* __restrict__ Q, const unsigned short* __restrict__ K,
    const unsigned short* __restrict__ V, unsigned short* __restrict__ O,
    int ld) {
    __shared__ __align__(16) unsigned short Ks[64 * LDT_A];
    __shared__ __align__(16) unsigned short Vs[64 * LDT_A];  // Vs[d][key]
    __shared__ __align__(16) unsigned short Ps[64 * LDT_A];
    const int tid = threadIdx.x;
    const int w = tid >> 6, lane = tid & 63;
    const int quad = lane >> 4, l16 = lane & 15;
    const int qblk = blockIdx.x, hh = blockIdx.y, bb = blockIdx.z;
    const int q0 = qblk * 64;
    const size_t seqbase = (size_t)bb * 2048;
    const int hoff = hh * 64;

    const unsigned short* qrow = Q + (seqbase + q0 + w * 16 + l16) * ld + hoff;
    const bf16x8_t qf0 = as_bf(*(const u16x8*)(qrow + quad * 8));
    const bf16x8_t qf1 = as_bf(*(const u16x8*)(qrow + 32 + quad * 8));

    f32x4_t o[4];
#pragma unroll
    for (int jd = 0; jd < 4; jd++) o[jd] = f32x4_t{0.f, 0.f, 0.f, 0.f};
    float m_r[4], l_r[4];
#pragma unroll
    for (int r = 0; r < 4; r++) { m_r[r] = -1e30f; l_r[r] = 0.f; }

    const int srow = tid >> 2;
    const int scol = (tid & 3) * 16;
    const int rowg = q0 + w * 16 + quad * 4;

    for (int t = 0; t <= qblk; ++t) {
        {
            const unsigned short* ksrc = K + (seqbase + t * 64 + srow) * ld + hoff + scol;
            const unsigned short* vsrc = V + (seqbase + t * 64 + srow) * ld + hoff + scol;
            u16x8 k0v = *(const u16x8*)ksrc;
            u16x8 k1v = *(const u16x8*)(ksrc + 8);
            u16x8 v0v = *(const u16x8*)vsrc;
            u16x8 v1v = *(const u16x8*)(vsrc + 8);
            *(u16x8*)&Ks[srow * LDT_A + scol] = k0v;
            *(u16x8*)&Ks[srow * LDT_A + scol + 8] = k1v;
#pragma unroll
            for (int i = 0; i < 8; i++) Vs[(scol + i) * LDT_A + srow] = v0v[i];
#pragma unroll
            for (int i = 0; i < 8; i++) Vs[(scol + 8 + i) * LDT_A + srow] = v1v[i];
        }
        __syncthreads();

        f32x4_t s[4];
#pragma unroll
        for (int jn = 0; jn < 4; jn++) {
            bf16x8_t kf0 = as_bf(*(const u16x8*)&Ks[(jn * 16 + l16) * LDT_A + quad * 8]);
            bf16x8_t kf1 = as_bf(*(const u16x8*)&Ks[(jn * 16 + l16) * LDT_A + 32 + quad * 8]);
            f32x4_t z = f32x4_t{0.f, 0.f, 0.f, 0.f};
            z = __builtin_amdgcn_mfma_f32_16x16x32_bf16(qf0, kf0, z, 0, 0, 0);
            z = __builtin_amdgcn_mfma_f32_16x16x32_bf16(qf1, kf1, z, 0, 0, 0);
            s[jn] = z;
        }
#pragma unroll
        for (int jn = 0; jn < 4; jn++) {
            const int col = t * 64 + jn * 16 + l16;
#pragma unroll
            for (int r = 0; r < 4; r++) {
                float val = s[jn][r] * 0.125f;
                s[jn][r] = (col <= rowg + r) ? val : -1e30f;
            }
        }
        float alpha[4];
#pragma unroll
        for (int r = 0; r < 4; r++) {
            float mx = fmaxf(fmaxf(s[0][r], s[1][r]), fmaxf(s[2][r], s[3][r]));
            mx = fmaxf(mx, __shfl_xor(mx, 1));
            mx = fmaxf(mx, __shfl_xor(mx, 2));
            mx = fmaxf(mx, __shfl_xor(mx, 4));
            mx = fmaxf(mx, __shfl_xor(mx, 8));
            const float mnew = fmaxf(m_r[r], mx);
            alpha[r] = __expf(m_r[r] - mnew);
            m_r[r] = mnew;
            float sum = 0.f;
#pragma unroll
            for (int jn = 0; jn < 4; jn++) {
                float p = __expf(s[jn][r] - mnew);
                s[jn][r] = p;
                sum += p;
            }
            sum += __shfl_xor(sum, 1);
            sum += __shfl_xor(sum, 2);
            sum += __shfl_xor(sum, 4);
            sum += __shfl_xor(sum, 8);
            l_r[r] = l_r[r] * alpha[r] + sum;
#pragma unroll
            for (int jd = 0; jd < 4; jd++) o[jd][r] *= alpha[r];
        }
#pragma unroll
        for (int jn = 0; jn < 4; jn++)
#pragma unroll
            for (int r = 0; r < 4; r++)
                Ps[(w * 16 + quad * 4 + r) * LDT_A + jn * 16 + l16] = f2b(s[jn][r]);
        const bf16x8_t pf0 = as_bf(*(const u16x8*)&Ps[(w * 16 + l16) * LDT_A + quad * 8]);
        const bf16x8_t pf1 = as_bf(*(const u16x8*)&Ps[(w * 16 + l16) * LDT_A + 32 + quad * 8]);
#pragma unroll
        for (int jd = 0; jd < 4; jd++) {
            bf16x8_t vf0 = as_bf(*(const u16x8*)&Vs[(jd * 16 + l16) * LDT_A + quad * 8]);
            bf16x8_t vf1 = as_bf(*(const u16x8*)&Vs[(jd * 16 + l16) * LDT_A + 32 + quad * 8]);
            o[jd] = __builtin_amdgcn_mfma_f32_16x16x32_bf16(pf0, vf0, o[jd], 0, 0, 0);
            o[jd] = __builtin_amdgcn_mfma_f32_16x16x32_bf16(pf1, vf1, o[jd], 0, 0, 0);
        }
        __syncthreads();
    }

#pragma unroll
    for (int jd = 0; jd < 4; jd++)
#pragma unroll
        for (int r = 0; r < 4; r++) {
            float val = o[jd][r] / l_r[r];
            O[(seqbase + rowg + r) * 1024 + hoff + jd * 16 + l16] = f2b(val);
        }
}

// ---------------------------------------------------------------- launch
extern "C" void kernel_launch(void* const* d_in, const int* in_sizes, int n_in,
                              void* d_out, int out_size, void* d_ws, size_t ws_size,
                              hipStream_t stream) {
    const float* x = (const float*)d_in[0];
    const float* ln1s = (const float*)d_in[1];
    const float* ln1b = (const float*)d_in[2];
    const float* ln2s = (const float*)d_in[3];
    const float* ln2b = (const float*)d_in[4];
    const float* wq = (const float*)d_in[5];
    const float* bq = (const float*)d_in[6];
    const float* wk = (const float*)d_in[7];
    const float* bk = (const float*)d_in[8];
    const float* wv = (const float*)d_in[9];
    const float* bv = (const float*)d_in[10];
    const float* wo = (const float*)d_in[11];
    const float* bo = (const float*)d_in[12];
    const float* w1 = (const float*)d_in[13];
    const float* b1 = (const float*)d_in[14];
    const float* w2 = (const float*)d_in[15];
    const float* b2 = (const float*)d_in[16];
    float* out = (float*)d_out;

    char* ws = (char*)d_ws;
    const size_t MB = 1u << 20;
    unsigned short* wqkvt = (unsigned short*)(ws + 0 * MB);   // [3072][1024]
    unsigned short* wot   = (unsigned short*)(ws + 6 * MB);   // [1024][1024]
    unsigned short* w1t   = (unsigned short*)(ws + 8 * MB);   // [4096][1024]
    unsigned short* w2t   = (unsigned short*)(ws + 16 * MB);  // [1024][4096]
    unsigned short* h     = (unsigned short*)(ws + 24 * MB);  // [4096][1024]
    unsigned short* qkv   = (unsigned short*)(ws + 32 * MB);  // [4096][3072]
    unsigned short* ctx   = (unsigned short*)(ws + 56 * MB);  // [4096][1024]
    unsigned short* h2    = (unsigned short*)(ws + 24 * MB);  // reuses h
    float*          x1    = (float*)(ws + 64 * MB);           // [4096][1024] fp32
    unsigned short* g     = (unsigned short*)(ws + 32 * MB);  // [4096][4096] reuses qkv+ctx

    const dim3 blk(256);

    // 0) weights -> transposed bf16
    transpose_cast<<<dim3(32, 32), blk, 0, stream>>>(wq, wqkvt, 1024, 1024);
    transpose_cast<<<dim3(32, 32), blk, 0, stream>>>(wk, wqkvt + (1u << 20), 1024, 1024);
    transpose_cast<<<dim3(32, 32), blk, 0, stream>>>(wv, wqkvt + (2u << 20), 1024, 1024);
    transpose_cast<<<dim3(32, 32), blk, 0, stream>>>(wo, wot, 1024, 1024);
    transpose_cast<<<dim3(32, 128), blk, 0, stream>>>(w1, w1t, 1024, 4096);
    transpose_cast<<<dim3(128, 32), blk, 0, stream>>>(w2, w2t, 4096, 1024);

    // 1) h = LN1(x)
    ln_kernel<<<4096, blk, 0, stream>>>(x, ln1s, ln1b, h);
    // 2) qkv = h @ [wq|wk|wv] + [bq|bk|bv]   (M=4096, N=3072, K=1024)
    gemm_kernel<128, 0, unsigned short><<<dim3(32, 24), blk, 0, stream>>>(
        h, wqkvt, bq, bk, bv, bv, nullptr, qkv, 4096, 3072, 1024);
    // 3) ctx = causal_attention(q,k,v)
    attn_kernel<<<dim3(32, 16, 2), blk, 0, stream>>>(qkv, qkv + 1024, qkv + 2048, ctx, 3072);
    // 4) x1 = ctx @ wo + bo + x   (fp32 out)
    gemm_kernel<64, 1, float><<<dim3(32, 16), blk, 0, stream>>>(
        ctx, wot, bo, bo, bo, bo, x, x1, 4096, 1024, 1024);
    // 5) h2 = LN2(x1)
    ln_kernel<<<4096, blk, 0, stream>>>(x1, ln2s, ln2b, h2);
    // 6) g = gelu(h2 @ w1 + b1)   (M=4096, N=4096, K=1024)
    gemm_kernel<128, 2, unsigned short><<<dim3(32, 32), blk, 0, stream>>>(
        h2, w1t, b1, b1 + 1024, b1 + 2048, b1 + 3072, nullptr, g, 4096, 4096, 1024);
    // 7) out = g @ w2 + b2 + x1   (M=4096, N=1024, K=4096, fp32 out)
    gemm_kernel<64, 1, float><<<dim3(32, 16), blk, 0, stream>>>(
        g, w2t, b2, b2, b2, b2, x1, out, 4096, 1024, 4096);
}